// Round 2
// baseline (300.184 us; speedup 1.0000x reference)
//
#include <hip/hip_runtime.h>
#include <hip/hip_bf16.h>
#include <math.h>

#define NUM_CLASSES 124
#define NCLS_PAD    128
#define FEAT_CH     64
#define OUT_HW      480
#define IN_HW       120
#define NPIX        (OUT_HW * OUT_HW)
#define NCELL       (IN_HW * IN_HW)
#define NCHUNK      (NPIX / 32)         // 7200 chunks of 32 px (15 per row)
#define EPSV        1e-8f

// acc row stride 68: (kg*4+r)*68 + 16t + n  ->  bank = kg*16 + 4r + 16t + n (mod 32)
// => kg pairs {0,2},{1,3} alias = 2-way = free (m136). 65 gave 4-way.
#define STRIDE_ACC   68
#define ACC_FLOATS   (NCLS_PAD * STRIDE_ACC)           // 8704
#define ACC_TOTAL    (ACC_FLOATS + NCLS_PAD)           // 8832

// ws layout (floats): mn[7936 permuted] | acc[8832] | fT[14400*64 permuted]
#define WS_MN   0
#define WS_ACC  (NUM_CLASSES * FEAT_CH)
#define WS_FT   (WS_ACC + ACC_TOTAL)

#define NTILE   (NCELL / 64)            // 225 transpose tiles
#define NZB     ((ACC_TOTAL + 255) / 256)  // 35 zero blocks

typedef short  v8s __attribute__((ext_vector_type(8)));
typedef float  v4f __attribute__((ext_vector_type(4)));

__device__ __forceinline__ short f2bf(float x) {
    __hip_bfloat16 h = __float2bfloat16(x);
    return __builtin_bit_cast(short, h);
}

// channel c -> packed slot: (c&15)*4 + (c>>4); lane n reads float4 at n*4 (= ch n,n+16,n+32,n+48)
__device__ __forceinline__ int chperm(int c) { return (c & 15) * 4 + (c >> 4); }

// ---- phase 0 (fused): normalize memory (permuted), zero acc, transpose to packed fT ----
__global__ __launch_bounds__(256) void k_prep(
        const float* __restrict__ mem, const float* __restrict__ feats,
        float* __restrict__ mn, float* __restrict__ acc, float* __restrict__ fT) {
    const int b = blockIdx.x;
    if (b < NUM_CLASSES) {
        if (threadIdx.x < FEAT_CH) {
            const int c = b, k = threadIdx.x;
            float v = mem[c * FEAT_CH + k];
            float s = v * v;
#pragma unroll
            for (int off = 32; off; off >>= 1) s += __shfl_xor(s, off);
            mn[c * FEAT_CH + chperm(k)] = v / fmaxf(sqrtf(s), EPSV);
        }
    } else if (b < NUM_CLASSES + NZB) {
        const int i = (b - NUM_CLASSES) * 256 + threadIdx.x;
        if (i < ACC_TOTAL) acc[i] = 0.0f;
    } else {
        __shared__ float tileL[64 * 65];
        const int t = b - NUM_CLASSES - NZB;       // 0..224
        const int q0 = t * 64;
        const int tid = threadIdx.x;
#pragma unroll
        for (int i = 0; i < 16; ++i) {
            const int idx = i * 256 + tid;
            const int k = idx >> 6, q = idx & 63;  // q fast -> coalesced read
            tileL[q * 65 + k] = feats[k * NCELL + q0 + q];
        }
        __syncthreads();
#pragma unroll
        for (int i = 0; i < 16; ++i) {
            const int idx = i * 256 + tid;
            const int q = idx >> 6, k = idx & 63;  // k fast -> within-256B-segment write
            fT[(q0 + q) * FEAT_CH + chperm(k)] = tileL[q * 65 + k];
        }
    }
}

// ---- DPP rotational butterfly: all-lanes sum within rows of 16 ---------------
template <int CTRL>
__device__ __forceinline__ float dpp_ror_add(float x) {
    int v = __builtin_amdgcn_update_dpp(0, __float_as_int(x), CTRL, 0xF, 0xF, false);
    return x + __int_as_float(v);
}
__device__ __forceinline__ void reduce16_pair(float& a, float& b) {
    a = dpp_ror_add<0x128>(a); b = dpp_ror_add<0x128>(b);   // row_ror:8
    a = dpp_ror_add<0x124>(a); b = dpp_ror_add<0x124>(b);   // row_ror:4
    a = dpp_ror_add<0x122>(a); b = dpp_ror_add<0x122>(b);   // row_ror:2
    a = dpp_ror_add<0x121>(a); b = dpp_ror_add<0x121>(b);   // row_ror:1
}

// ---- phase 1: one-hot MFMA accumulation --------------------------------------
// 256 blocks x 512 thr (1 resident block/CU at 2 waves/SIMD). Each wave owns a
// contiguous range of 3-4 chunks (row-locality in fT). float4-packed fT/mn:
// 8+8 dwordx4 loads/chunk. Interior cols use compile-time (L,tx) fast path.
// Epilogue: all waves ds_add_f32 into accL concurrently (2-way banks, free),
// then nonzero rows atomicAdd straight to global acc (no partials kernel).
__global__ __launch_bounds__(512, 2) void k_accum(
        const float* __restrict__ fT, const int* __restrict__ seg,
        const float* __restrict__ mn, float* __restrict__ acc) {
    __shared__ float accL[ACC_FLOATS];
    __shared__ float cntL[NCLS_PAD];

    const int tid = threadIdx.x;
    for (int i = tid; i < ACC_FLOATS; i += 512) accL[i] = 0.0f;
    if (tid < NCLS_PAD) cntL[tid] = 0.0f;
    __syncthreads();

    const int lane = tid & 63;
    const int n  = lane & 15;         // ch within tile / class within band
    const int kg = lane >> 4;         // pixel-group (8 px each)
    const int widx = tid >> 6;        // wave in block (0..7)
    const int gwave = blockIdx.x * 8 + widx;
    const int nw = gridDim.x * 8;

    v4f C[8][4];
#pragma unroll
    for (int b = 0; b < 8; ++b)
#pragma unroll
        for (int t = 0; t < 4; ++t) C[b][t] = (v4f)0.0f;

    const int chA = (int)(((long long)gwave * NCHUNK) / nw);
    const int chB = (int)(((long long)(gwave + 1) * NCHUNK) / nw);

    for (int ch = chA; ch < chB; ++ch) {
        const int oy  = ch / 15;
        const int col = ch - oy * 15;
        const int px0 = col * 32 + kg * 8;
        float fy = fminf(fmaxf(oy * 0.25f - 0.375f, 0.0f), 119.0f);
        const int y0 = (int)fy; const float ty = fy - (float)y0;
        const int y1 = min(y0 + 1, IN_HW - 1);
        const int base = px0 >> 2;
        const int c0 = max(base - 1, 0), c1 = base;
        const int c2 = min(base + 1, IN_HW - 1), c3 = min(base + 2, IN_HW - 1);
        const int r0 = y0 * IN_HW, r1 = y1 * IN_HW;

        int segj[8];
        {
            const int4* sp = (const int4*)(seg + oy * OUT_HW + px0);
            int4 s0 = sp[0], s1 = sp[1];
            segj[0]=s0.x; segj[1]=s0.y; segj[2]=s0.z; segj[3]=s0.w;
            segj[4]=s1.x; segj[5]=s1.y; segj[6]=s1.z; segj[7]=s1.w;
        }

        const int nb4 = n * 4;
        v4f T0 = *(const v4f*)(fT + (size_t)(r0 + c0) * FEAT_CH + nb4);
        v4f T1 = *(const v4f*)(fT + (size_t)(r0 + c1) * FEAT_CH + nb4);
        v4f T2 = *(const v4f*)(fT + (size_t)(r0 + c2) * FEAT_CH + nb4);
        v4f T3 = *(const v4f*)(fT + (size_t)(r0 + c3) * FEAT_CH + nb4);
        v4f B0 = *(const v4f*)(fT + (size_t)(r1 + c0) * FEAT_CH + nb4);
        v4f B1 = *(const v4f*)(fT + (size_t)(r1 + c1) * FEAT_CH + nb4);
        v4f B2 = *(const v4f*)(fT + (size_t)(r1 + c2) * FEAT_CH + nb4);
        v4f B3 = *(const v4f*)(fT + (size_t)(r1 + c3) * FEAT_CH + nb4);
        v4f M[8];
#pragma unroll
        for (int j = 0; j < 8; ++j)
            M[j] = *(const v4f*)(mn + (size_t)segj[j] * FEAT_CH + nb4);

        float nr[8], dt[8];
#pragma unroll
        for (int j = 0; j < 8; ++j) { nr[j] = 0.0f; dt[j] = 0.0f; }
        v8s Bfrag[4];

        if (col != 0 && col != 14) {
            // interior: (L,tx) per j is compile-time; bit-identical to generic
#pragma unroll
            for (int t = 0; t < 4; ++t) {
                const float a0=T0[t], a1=T1[t], a2=T2[t], a3=T3[t];
                const float e0=B0[t], e1=B1[t], e2=B2[t], e3=B3[t];
                const float dA1=a1-a0, dA2=a2-a1, dA3=a3-a2;
                const float dE1=e1-e0, dE2=e2-e1, dE3=e3-e2;
#define PXI(J, TX, AL, DA, EL, DE) { \
                float tp = fmaf(TX, DA, AL); \
                float bt = fmaf(TX, DE, EL); \
                float v  = fmaf(ty, bt - tp, tp); \
                nr[J] = fmaf(v, v, nr[J]); \
                dt[J] = fmaf(v, M[J][t], dt[J]); \
                Bfrag[t][J] = f2bf(v); }
                PXI(0, 0.625f, a0, dA1, e0, dE1)
                PXI(1, 0.875f, a0, dA1, e0, dE1)
                PXI(2, 0.125f, a1, dA2, e1, dE2)
                PXI(3, 0.375f, a1, dA2, e1, dE2)
                PXI(4, 0.625f, a1, dA2, e1, dE2)
                PXI(5, 0.875f, a1, dA2, e1, dE2)
                PXI(6, 0.125f, a2, dA3, e2, dE3)
                PXI(7, 0.375f, a2, dA3, e2, dE3)
#undef PXI
            }
        } else {
            float txj[8]; int Lj[8];
#pragma unroll
            for (int j = 0; j < 8; ++j) {
                float fx = fminf(fmaxf((float)(px0 + j) * 0.25f - 0.375f, 0.0f), 119.0f);
                int x0 = (int)fx; txj[j] = fx - (float)x0; Lj[j] = x0 - base + 1;  // 0..2
            }
#pragma unroll
            for (int t = 0; t < 4; ++t) {
                const float a0=T0[t], a1=T1[t], a2=T2[t], a3=T3[t];
                const float e0=B0[t], e1=B1[t], e2=B2[t], e3=B3[t];
#pragma unroll
                for (int j = 0; j < 8; ++j) {
                    const int L = Lj[j];
                    float tl = (L==0)?a0:((L==1)?a1:a2);
                    float tr = (L==0)?a1:((L==1)?a2:a3);
                    float bl = (L==0)?e0:((L==1)?e1:e2);
                    float br = (L==0)?e1:((L==1)?e2:e3);
                    float tp = fmaf(txj[j], tr - tl, tl);
                    float bt = fmaf(txj[j], br - bl, bl);
                    float v  = fmaf(ty, bt - tp, tp);
                    nr[j] = fmaf(v, v, nr[j]);
                    dt[j] = fmaf(v, M[j][t], dt[j]);
                    Bfrag[t][j] = f2bf(v);
                }
            }
        }

        // per-pixel reduce over 16 ch-lanes (within the kg row of 16)
#pragma unroll
        for (int j = 0; j < 8; ++j) reduce16_pair(nr[j], dt[j]);

        float wj[8]; short wb[8];
#pragma unroll
        for (int j = 0; j < 8; ++j) {
            wj[j] = 1.0f - dt[j] / fmaxf(sqrtf(nr[j]), EPSV);  // mn==0 rows -> w==1
            wb[j] = f2bf(wj[j]);
        }
        // one-hot A per class band, 4 MFMAs each
#pragma unroll
        for (int b = 0; b < 8; ++b) {
            v8s A;
#pragma unroll
            for (int j = 0; j < 8; ++j)
                A[j] = (segj[j] == b * 16 + n) ? wb[j] : (short)0;
#pragma unroll
            for (int t = 0; t < 4; ++t)
                C[b][t] = __builtin_amdgcn_mfma_f32_16x16x32_bf16(A, Bfrag[t], C[b][t], 0, 0, 0);
        }
        // wsum / count (LDS atomics, lanes n==0 only)
        if (n == 0) {
#pragma unroll
            for (int j = 0; j < 8; ++j) {
                atomicAdd(&accL[segj[j] * STRIDE_ACC + FEAT_CH], wj[j]);
                atomicAdd(&cntL[segj[j]], 1.0f);
            }
        }
    }

    // concurrent merge: all waves ds_add_f32 into accL in parallel (no barrier
    // needed vs main-loop stragglers: every accL access is atomic; merge cols
    // 0..63 are disjoint from the wsum col 64). Banks are 2-way = free.
#pragma unroll
    for (int b = 0; b < 8; ++b)
#pragma unroll
        for (int t = 0; t < 4; ++t)
#pragma unroll
            for (int r = 0; r < 4; ++r)
                atomicAdd(&accL[(b * 16 + kg * 4 + r) * STRIDE_ACC + t * 16 + n],
                          C[b][t][r]);
    __syncthreads();

    // writeout: nonzero slots atomicAdd straight to global acc (part/k_reduce gone).
    // NOTE: lane is 0..63 — lane 0 handles the wsum slot (col 64) and the count.
    for (int row = widx; row < NCLS_PAD; row += 8) {
        const float v = accL[row * STRIDE_ACC + lane];
        if (v != 0.0f) atomicAdd(&acc[row * STRIDE_ACC + lane], v);
        if (lane == 0) {
            const float w = accL[row * STRIDE_ACC + FEAT_CH];
            if (w != 0.0f) atomicAdd(&acc[row * STRIDE_ACC + FEAT_CH], w);
            const float cv = cntL[row];
            if (cv != 0.0f) atomicAdd(&acc[ACC_FLOATS + row], cv);
        }
    }
}

// ---- phase 2: momentum / is_zero / present selects ---------------------------
__global__ void k_final(const float* __restrict__ acc, const float* __restrict__ mem,
                        float* __restrict__ out) {
    const int c = blockIdx.x, k = threadIdx.x;   // 124 blocks x 64 threads (1 wave)
    const float a    = acc[c * STRIDE_ACC + k];
    const float wsum = acc[c * STRIDE_ACC + FEAT_CH];
    const float cnt  = acc[ACC_FLOATS + c];
    const float m = mem[c * FEAT_CH + k];
    const int is_zero = __all(m == 0.0f);
    const float divisor = (wsum > 0.0f) ? wsum : 1.0f;
    const float val = a / divisor;
    const float nw = is_zero ? val : fmaf(0.1f, val, 0.9f * m);
    out[c * FEAT_CH + k] = (cnt > 0.0f) ? nw : m;
}

extern "C" void kernel_launch(void* const* d_in, const int* in_sizes, int n_in,
                              void* d_out, int out_size, void* d_ws, size_t ws_size,
                              hipStream_t stream) {
    const float* feats  = (const float*)d_in[0];   // (1,64,120,120) f32
    const float* memory = (const float*)d_in[1];   // (124,1,64) f32
    const int*   seg    = (const int*)d_in[2];     // (1,480,480) i32
    float* out = (float*)d_out;                    // (124,1,64) f32
    float* ws  = (float*)d_ws;

    float* mn  = ws + WS_MN;
    float* acc = ws + WS_ACC;
    float* fT  = ws + WS_FT;

    k_prep<<<NUM_CLASSES + NZB + NTILE, 256, 0, stream>>>(memory, feats, mn, acc, fT);
    k_accum<<<256, 512, 0, stream>>>(fT, seg, mn, acc);
    k_final<<<NUM_CLASSES, FEAT_CH, 0, stream>>>(acc, memory, out);
}

// Round 3
// 188.991 us; speedup vs baseline: 1.5883x; 1.5883x over previous
//
#include <hip/hip_runtime.h>
#include <hip/hip_bf16.h>
#include <math.h>

#define NUM_CLASSES 124
#define NCLS_PAD    128
#define FEAT_CH     64
#define OUT_HW      480
#define IN_HW       120
#define NPIX        (OUT_HW * OUT_HW)
#define NCELL       (IN_HW * IN_HW)
#define NCHUNK      (NPIX / 32)         // 7200 chunks of 32 px (15 per row)
#define EPSV        1e-8f

// acc row stride 68: (kg*4+r)*68 + 16t + n  ->  bank = kg*16 + 4r + 16t + n (mod 32)
// => kg pairs {0,2},{1,3} alias = 2-way = free (m136). 65 gave 4-way.
#define STRIDE_ACC   68
#define ACC_FLOATS   (NCLS_PAD * STRIDE_ACC)           // 8704
#define ACC_TOTAL    (ACC_FLOATS + NCLS_PAD)           // 8832

#define NRED    8

// ws layout (floats): mn[7936 permuted] | red[8*8832] | fT[14400*64 permuted] | part[nb*8832]
#define WS_MN   0
#define WS_RED  (NUM_CLASSES * FEAT_CH)
#define WS_FT   (WS_RED + NRED * ACC_TOTAL)
#define WS_PART (WS_FT + NCELL * FEAT_CH)

#define NTILE   (NCELL / 64)            // 225 transpose tiles

typedef short  v8s __attribute__((ext_vector_type(8)));
typedef float  v4f __attribute__((ext_vector_type(4)));

__device__ __forceinline__ short f2bf(float x) {
    __hip_bfloat16 h = __float2bfloat16(x);
    return __builtin_bit_cast(short, h);
}

// channel c -> packed slot: (c&15)*4 + (c>>4); lane n reads float4 at n*4 (= ch n,n+16,n+32,n+48)
__device__ __forceinline__ int chperm(int c) { return (c & 15) * 4 + (c >> 4); }

// ---- phase 0 (fused): normalize memory (permuted), transpose to packed fT ----
__global__ __launch_bounds__(256) void k_prep(
        const float* __restrict__ mem, const float* __restrict__ feats,
        float* __restrict__ mn, float* __restrict__ fT) {
    const int b = blockIdx.x;
    if (b < NUM_CLASSES) {
        if (threadIdx.x < FEAT_CH) {
            const int c = b, k = threadIdx.x;
            float v = mem[c * FEAT_CH + k];
            float s = v * v;
#pragma unroll
            for (int off = 32; off; off >>= 1) s += __shfl_xor(s, off);
            mn[c * FEAT_CH + chperm(k)] = v / fmaxf(sqrtf(s), EPSV);
        }
    } else {
        __shared__ float tileL[64 * 65];
        const int t = b - NUM_CLASSES;             // 0..224
        const int q0 = t * 64;
        const int tid = threadIdx.x;
#pragma unroll
        for (int i = 0; i < 16; ++i) {
            const int idx = i * 256 + tid;
            const int k = idx >> 6, q = idx & 63;  // q fast -> coalesced read
            tileL[q * 65 + k] = feats[k * NCELL + q0 + q];
        }
        __syncthreads();
#pragma unroll
        for (int i = 0; i < 16; ++i) {
            const int idx = i * 256 + tid;
            const int q = idx >> 6, k = idx & 63;  // k fast -> within-256B-segment write
            fT[(q0 + q) * FEAT_CH + chperm(k)] = tileL[q * 65 + k];
        }
    }
}

// ---- DPP rotational butterfly: all-lanes sum within rows of 16 ---------------
template <int CTRL>
__device__ __forceinline__ float dpp_ror_add(float x) {
    int v = __builtin_amdgcn_update_dpp(0, __float_as_int(x), CTRL, 0xF, 0xF, false);
    return x + __int_as_float(v);
}
__device__ __forceinline__ void reduce16_pair(float& a, float& b) {
    a = dpp_ror_add<0x128>(a); b = dpp_ror_add<0x128>(b);   // row_ror:8
    a = dpp_ror_add<0x124>(a); b = dpp_ror_add<0x124>(b);   // row_ror:4
    a = dpp_ror_add<0x122>(a); b = dpp_ror_add<0x122>(b);   // row_ror:2
    a = dpp_ror_add<0x121>(a); b = dpp_ror_add<0x121>(b);   // row_ror:1
}

// ---- phase 1: one-hot MFMA accumulation --------------------------------------
// nb blocks x 512 thr. Each wave owns a contiguous range of chunks (row-locality
// in fT). float4-packed fT/mn: 8+8 dwordx4 loads/chunk. Interior cols use
// compile-time (L,tx) fast path. Epilogue: all waves ds_add_f32 into accL
// concurrently (2-way banks, free), then PLAIN coalesced stores to part.
// (Round-2 lesson: 2M device atomics = 134 MB of 64B RMW HBM writes = 247 us.)
__global__ __launch_bounds__(512, 2) void k_accum(
        const float* __restrict__ fT, const int* __restrict__ seg,
        const float* __restrict__ mn, float* __restrict__ part) {
    __shared__ __align__(16) float accL[ACC_FLOATS];
    __shared__ float cntL[NCLS_PAD];

    const int tid = threadIdx.x;
    for (int i = tid; i < ACC_FLOATS; i += 512) accL[i] = 0.0f;
    if (tid < NCLS_PAD) cntL[tid] = 0.0f;
    __syncthreads();

    const int lane = tid & 63;
    const int n  = lane & 15;         // ch within tile / class within band
    const int kg = lane >> 4;         // pixel-group (8 px each)
    const int widx = tid >> 6;        // wave in block (0..7)
    const int gwave = blockIdx.x * 8 + widx;
    const int nw = gridDim.x * 8;

    v4f C[8][4];
#pragma unroll
    for (int b = 0; b < 8; ++b)
#pragma unroll
        for (int t = 0; t < 4; ++t) C[b][t] = (v4f)0.0f;

    const int chA = (int)(((long long)gwave * NCHUNK) / nw);
    const int chB = (int)(((long long)(gwave + 1) * NCHUNK) / nw);

    for (int ch = chA; ch < chB; ++ch) {
        const int oy  = ch / 15;
        const int col = ch - oy * 15;
        const int px0 = col * 32 + kg * 8;
        float fy = fminf(fmaxf(oy * 0.25f - 0.375f, 0.0f), 119.0f);
        const int y0 = (int)fy; const float ty = fy - (float)y0;
        const int y1 = min(y0 + 1, IN_HW - 1);
        const int base = px0 >> 2;
        const int c0 = max(base - 1, 0), c1 = base;
        const int c2 = min(base + 1, IN_HW - 1), c3 = min(base + 2, IN_HW - 1);
        const int r0 = y0 * IN_HW, r1 = y1 * IN_HW;

        int segj[8];
        {
            const int4* sp = (const int4*)(seg + oy * OUT_HW + px0);
            int4 s0 = sp[0], s1 = sp[1];
            segj[0]=s0.x; segj[1]=s0.y; segj[2]=s0.z; segj[3]=s0.w;
            segj[4]=s1.x; segj[5]=s1.y; segj[6]=s1.z; segj[7]=s1.w;
        }

        const int nb4 = n * 4;
        v4f T0 = *(const v4f*)(fT + (size_t)(r0 + c0) * FEAT_CH + nb4);
        v4f T1 = *(const v4f*)(fT + (size_t)(r0 + c1) * FEAT_CH + nb4);
        v4f T2 = *(const v4f*)(fT + (size_t)(r0 + c2) * FEAT_CH + nb4);
        v4f T3 = *(const v4f*)(fT + (size_t)(r0 + c3) * FEAT_CH + nb4);
        v4f B0 = *(const v4f*)(fT + (size_t)(r1 + c0) * FEAT_CH + nb4);
        v4f B1 = *(const v4f*)(fT + (size_t)(r1 + c1) * FEAT_CH + nb4);
        v4f B2 = *(const v4f*)(fT + (size_t)(r1 + c2) * FEAT_CH + nb4);
        v4f B3 = *(const v4f*)(fT + (size_t)(r1 + c3) * FEAT_CH + nb4);
        v4f M[8];
#pragma unroll
        for (int j = 0; j < 8; ++j)
            M[j] = *(const v4f*)(mn + (size_t)segj[j] * FEAT_CH + nb4);

        float nr[8], dt[8];
#pragma unroll
        for (int j = 0; j < 8; ++j) { nr[j] = 0.0f; dt[j] = 0.0f; }
        v8s Bfrag[4];

        if (col != 0 && col != 14) {
            // interior: (L,tx) per j is compile-time; bit-identical to generic
#pragma unroll
            for (int t = 0; t < 4; ++t) {
                const float a0=T0[t], a1=T1[t], a2=T2[t], a3=T3[t];
                const float e0=B0[t], e1=B1[t], e2=B2[t], e3=B3[t];
                const float dA1=a1-a0, dA2=a2-a1, dA3=a3-a2;
                const float dE1=e1-e0, dE2=e2-e1, dE3=e3-e2;
#define PXI(J, TX, AL, DA, EL, DE) { \
                float tp = fmaf(TX, DA, AL); \
                float bt = fmaf(TX, DE, EL); \
                float v  = fmaf(ty, bt - tp, tp); \
                nr[J] = fmaf(v, v, nr[J]); \
                dt[J] = fmaf(v, M[J][t], dt[J]); \
                Bfrag[t][J] = f2bf(v); }
                PXI(0, 0.625f, a0, dA1, e0, dE1)
                PXI(1, 0.875f, a0, dA1, e0, dE1)
                PXI(2, 0.125f, a1, dA2, e1, dE2)
                PXI(3, 0.375f, a1, dA2, e1, dE2)
                PXI(4, 0.625f, a1, dA2, e1, dE2)
                PXI(5, 0.875f, a1, dA2, e1, dE2)
                PXI(6, 0.125f, a2, dA3, e2, dE3)
                PXI(7, 0.375f, a2, dA3, e2, dE3)
#undef PXI
            }
        } else {
            float txj[8]; int Lj[8];
#pragma unroll
            for (int j = 0; j < 8; ++j) {
                float fx = fminf(fmaxf((float)(px0 + j) * 0.25f - 0.375f, 0.0f), 119.0f);
                int x0 = (int)fx; txj[j] = fx - (float)x0; Lj[j] = x0 - base + 1;  // 0..2
            }
#pragma unroll
            for (int t = 0; t < 4; ++t) {
                const float a0=T0[t], a1=T1[t], a2=T2[t], a3=T3[t];
                const float e0=B0[t], e1=B1[t], e2=B2[t], e3=B3[t];
#pragma unroll
                for (int j = 0; j < 8; ++j) {
                    const int L = Lj[j];
                    float tl = (L==0)?a0:((L==1)?a1:a2);
                    float tr = (L==0)?a1:((L==1)?a2:a3);
                    float bl = (L==0)?e0:((L==1)?e1:e2);
                    float br = (L==0)?e1:((L==1)?e2:e3);
                    float tp = fmaf(txj[j], tr - tl, tl);
                    float bt = fmaf(txj[j], br - bl, bl);
                    float v  = fmaf(ty, bt - tp, tp);
                    nr[j] = fmaf(v, v, nr[j]);
                    dt[j] = fmaf(v, M[j][t], dt[j]);
                    Bfrag[t][j] = f2bf(v);
                }
            }
        }

        // per-pixel reduce over 16 ch-lanes (within the kg row of 16)
#pragma unroll
        for (int j = 0; j < 8; ++j) reduce16_pair(nr[j], dt[j]);

        float wj[8]; short wb[8];
#pragma unroll
        for (int j = 0; j < 8; ++j) {
            wj[j] = 1.0f - dt[j] / fmaxf(sqrtf(nr[j]), EPSV);  // mn==0 rows -> w==1
            wb[j] = f2bf(wj[j]);
        }
        // one-hot A per class band, 4 MFMAs each
#pragma unroll
        for (int b = 0; b < 8; ++b) {
            v8s A;
#pragma unroll
            for (int j = 0; j < 8; ++j)
                A[j] = (segj[j] == b * 16 + n) ? wb[j] : (short)0;
#pragma unroll
            for (int t = 0; t < 4; ++t)
                C[b][t] = __builtin_amdgcn_mfma_f32_16x16x32_bf16(A, Bfrag[t], C[b][t], 0, 0, 0);
        }
        // wsum / count (LDS atomics, lanes n==0 only)
        if (n == 0) {
#pragma unroll
            for (int j = 0; j < 8; ++j) {
                atomicAdd(&accL[segj[j] * STRIDE_ACC + FEAT_CH], wj[j]);
                atomicAdd(&cntL[segj[j]], 1.0f);
            }
        }
    }

    // concurrent merge: all waves ds_add_f32 into accL in parallel (no barrier
    // needed vs main-loop stragglers: every accL access is atomic; merge cols
    // 0..63 are disjoint from the wsum col 64). Banks are 2-way = free.
#pragma unroll
    for (int b = 0; b < 8; ++b)
#pragma unroll
        for (int t = 0; t < 4; ++t)
#pragma unroll
            for (int r = 0; r < 4; ++r)
                atomicAdd(&accL[(b * 16 + kg * 4 + r) * STRIDE_ACC + t * 16 + n],
                          C[b][t][r]);
    __syncthreads();

    // writeout: plain coalesced dwordx4 stores of the block partial (no atomics)
    float* __restrict__ dst = part + (size_t)blockIdx.x * ACC_TOTAL;
    v4f* __restrict__ d4 = (v4f*)dst;
    const v4f* __restrict__ s4 = (const v4f*)accL;
    for (int i = tid; i < ACC_FLOATS / 4; i += 512) d4[i] = s4[i];
    if (tid < NCLS_PAD) dst[ACC_FLOATS + tid] = cntL[tid];
}

// ---- phase 1b: tree-reduce partials into red[NRED][ACC_TOTAL] (no atomics) ---
__global__ __launch_bounds__(256) void k_reduce(
        const float* __restrict__ part, float* __restrict__ red, int nb) {
    const int i = blockIdx.x * 256 + threadIdx.x;    // slot
    if (i >= ACC_TOTAL) return;
    const int chunk = (nb + NRED - 1) / NRED;
    const int b0 = blockIdx.y * chunk;
    const int b1 = min(nb, b0 + chunk);
    float s = 0.0f;
    for (int b = b0; b < b1; ++b) s += part[(size_t)b * ACC_TOTAL + i];
    red[(size_t)blockIdx.y * ACC_TOTAL + i] = s;
}

// ---- phase 2: sum group partials + momentum / is_zero / present selects ------
__global__ void k_final(const float* __restrict__ red, const float* __restrict__ mem,
                        float* __restrict__ out) {
    const int c = blockIdx.x, k = threadIdx.x;   // 124 blocks x 64 threads (1 wave)
    float a = 0.0f, wsum = 0.0f, cnt = 0.0f;
#pragma unroll
    for (int g = 0; g < NRED; ++g) {
        const float* r = red + (size_t)g * ACC_TOTAL;
        a    += r[c * STRIDE_ACC + k];
        wsum += r[c * STRIDE_ACC + FEAT_CH];
        cnt  += r[ACC_FLOATS + c];
    }
    const float m = mem[c * FEAT_CH + k];
    const int is_zero = __all(m == 0.0f);
    const float divisor = (wsum > 0.0f) ? wsum : 1.0f;
    const float val = a / divisor;
    const float nw = is_zero ? val : fmaf(0.1f, val, 0.9f * m);
    out[c * FEAT_CH + k] = (cnt > 0.0f) ? nw : m;
}

extern "C" void kernel_launch(void* const* d_in, const int* in_sizes, int n_in,
                              void* d_out, int out_size, void* d_ws, size_t ws_size,
                              hipStream_t stream) {
    const float* feats  = (const float*)d_in[0];   // (1,64,120,120) f32
    const float* memory = (const float*)d_in[1];   // (124,1,64) f32
    const int*   seg    = (const int*)d_in[2];     // (1,480,480) i32
    float* out = (float*)d_out;                    // (124,1,64) f32
    float* ws  = (float*)d_ws;

    float* mn   = ws + WS_MN;
    float* red  = ws + WS_RED;
    float* fT   = ws + WS_FT;
    float* part = ws + WS_PART;

    long long avail = (long long)(ws_size / 4) - WS_PART;
    const int nb = (avail >= (long long)256 * ACC_TOTAL) ? 256 : 128;

    k_prep<<<NUM_CLASSES + NTILE, 256, 0, stream>>>(memory, feats, mn, fT);
    k_accum<<<nb, 512, 0, stream>>>(fT, seg, mn, part);
    dim3 rg((ACC_TOTAL + 255) / 256, NRED);
    k_reduce<<<rg, 256, 0, stream>>>(part, red, nb);
    k_final<<<NUM_CLASSES, FEAT_CH, 0, stream>>>(red, memory, out);
}

// Round 4
// 183.185 us; speedup vs baseline: 1.6387x; 1.0317x over previous
//
#include <hip/hip_runtime.h>
#include <hip/hip_bf16.h>
#include <math.h>

#define NUM_CLASSES 124
#define NCLS_PAD    128
#define FEAT_CH     64
#define OUT_HW      480
#define IN_HW       120
#define NPIX        (OUT_HW * OUT_HW)
#define NCELL       (IN_HW * IN_HW)
#define NCHUNK      (NPIX / 32)         // 7200 chunks of 32 px (15 per row)
#define EPSV        1e-8f

// acc row stride 68: (kg*4+r)*68 + 16t + n  ->  bank = kg*16 + 4r + 16t + n (mod 32)
// => kg pairs {0,2},{1,3} alias = 2-way = free (m136).
#define STRIDE_ACC   68
#define ACC_FLOATS   (NCLS_PAD * STRIDE_ACC)           // 8704
#define ACC_TOTAL    (ACC_FLOATS + NCLS_PAD)           // 8832

#define NRED    8

// ws layout (floats): mn[7936 permuted] | red[8*8832] | fT[14400*64 permuted] | part[nb*8832]
#define WS_MN   0
#define WS_RED  (NUM_CLASSES * FEAT_CH)
#define WS_FT   (WS_RED + NRED * ACC_TOTAL)
#define WS_PART (WS_FT + NCELL * FEAT_CH)

#define NTILE   (NCELL / 64)            // 225 transpose tiles

typedef short  v8s __attribute__((ext_vector_type(8)));
typedef float  v4f __attribute__((ext_vector_type(4)));

__device__ __forceinline__ short f2bf(float x) {
    __hip_bfloat16 h = __float2bfloat16(x);
    return __builtin_bit_cast(short, h);
}

// channel c -> packed slot: (c&15)*4 + (c>>4); lane n reads float4 at n*4 (= ch n,n+16,n+32,n+48)
__device__ __forceinline__ int chperm(int c) { return (c & 15) * 4 + (c >> 4); }

// ---- phase 0 (fused): normalize memory (permuted), transpose to packed fT ----
__global__ __launch_bounds__(256) void k_prep(
        const float* __restrict__ mem, const float* __restrict__ feats,
        float* __restrict__ mn, float* __restrict__ fT) {
    const int b = blockIdx.x;
    if (b < NUM_CLASSES) {
        if (threadIdx.x < FEAT_CH) {
            const int c = b, k = threadIdx.x;
            float v = mem[c * FEAT_CH + k];
            float s = v * v;
#pragma unroll
            for (int off = 32; off; off >>= 1) s += __shfl_xor(s, off);
            mn[c * FEAT_CH + chperm(k)] = v / fmaxf(sqrtf(s), EPSV);
        }
    } else {
        __shared__ float tileL[64 * 65];
        const int t = b - NUM_CLASSES;             // 0..224
        const int q0 = t * 64;
        const int tid = threadIdx.x;
#pragma unroll
        for (int i = 0; i < 16; ++i) {
            const int idx = i * 256 + tid;
            const int k = idx >> 6, q = idx & 63;  // q fast -> coalesced read
            tileL[q * 65 + k] = feats[k * NCELL + q0 + q];
        }
        __syncthreads();
#pragma unroll
        for (int i = 0; i < 16; ++i) {
            const int idx = i * 256 + tid;
            const int q = idx >> 6, k = idx & 63;  // k fast -> within-256B-segment write
            fT[(q0 + q) * FEAT_CH + chperm(k)] = tileL[q * 65 + k];
        }
    }
}

// ---- DPP rotational butterfly: all-lanes sum within rows of 16 ---------------
template <int CTRL>
__device__ __forceinline__ float dpp_ror_add(float x) {
    int v = __builtin_amdgcn_update_dpp(0, __float_as_int(x), CTRL, 0xF, 0xF, false);
    return x + __int_as_float(v);
}
__device__ __forceinline__ void reduce16_pair(float& a, float& b) {
    a = dpp_ror_add<0x128>(a); b = dpp_ror_add<0x128>(b);   // row_ror:8
    a = dpp_ror_add<0x124>(a); b = dpp_ror_add<0x124>(b);   // row_ror:4
    a = dpp_ror_add<0x122>(a); b = dpp_ror_add<0x122>(b);   // row_ror:2
    a = dpp_ror_add<0x121>(a); b = dpp_ror_add<0x121>(b);   // row_ror:1
}

// ---- phase 1: one-hot MFMA accumulation --------------------------------------
// Register budget is THE constraint: C[8][4]=128 acc regs + 128 arch = 256 =
// the __launch_bounds__(512,2) budget. Round-3 lesson: hoisting M[8] (32 regs)
// on top of T/B (32 regs) spilled ~250B/lane/chunk = 115 MB scratch writes.
// Fix: j-outer loop — one M v4f live at a time; T/B stay hoisted (the reuse).
__global__ __launch_bounds__(512, 2) void k_accum(
        const float* __restrict__ fT, const int* __restrict__ seg,
        const float* __restrict__ mn, float* __restrict__ part) {
    __shared__ __align__(16) float accL[ACC_FLOATS];
    __shared__ float cntL[NCLS_PAD];

    const int tid = threadIdx.x;
    for (int i = tid; i < ACC_FLOATS; i += 512) accL[i] = 0.0f;
    if (tid < NCLS_PAD) cntL[tid] = 0.0f;
    __syncthreads();

    const int lane = tid & 63;
    const int n  = lane & 15;         // ch within tile / class within band
    const int kg = lane >> 4;         // pixel-group (8 px each)
    const int widx = tid >> 6;        // wave in block (0..7)
    const int gwave = blockIdx.x * 8 + widx;
    const int nw = gridDim.x * 8;

    v4f C[8][4];
#pragma unroll
    for (int b = 0; b < 8; ++b)
#pragma unroll
        for (int t = 0; t < 4; ++t) C[b][t] = (v4f)0.0f;

    const int chA = (int)(((long long)gwave * NCHUNK) / nw);
    const int chB = (int)(((long long)(gwave + 1) * NCHUNK) / nw);

    for (int ch = chA; ch < chB; ++ch) {
        const int oy  = ch / 15;
        const int col = ch - oy * 15;
        const int px0 = col * 32 + kg * 8;
        float fy = fminf(fmaxf(oy * 0.25f - 0.375f, 0.0f), 119.0f);
        const int y0 = (int)fy; const float ty = fy - (float)y0;
        const int y1 = min(y0 + 1, IN_HW - 1);
        const int base = px0 >> 2;
        const int c0 = max(base - 1, 0), c1 = base;
        const int c2 = min(base + 1, IN_HW - 1), c3 = min(base + 2, IN_HW - 1);
        const int r0 = y0 * IN_HW, r1 = y1 * IN_HW;

        int segj[8];
        {
            const int4* sp = (const int4*)(seg + oy * OUT_HW + px0);
            int4 s0 = sp[0], s1 = sp[1];
            segj[0]=s0.x; segj[1]=s0.y; segj[2]=s0.z; segj[3]=s0.w;
            segj[4]=s1.x; segj[5]=s1.y; segj[6]=s1.z; segj[7]=s1.w;
        }

        const int nb4 = n * 4;
        v4f T0 = *(const v4f*)(fT + (size_t)(r0 + c0) * FEAT_CH + nb4);
        v4f T1 = *(const v4f*)(fT + (size_t)(r0 + c1) * FEAT_CH + nb4);
        v4f T2 = *(const v4f*)(fT + (size_t)(r0 + c2) * FEAT_CH + nb4);
        v4f T3 = *(const v4f*)(fT + (size_t)(r0 + c3) * FEAT_CH + nb4);
        v4f B0 = *(const v4f*)(fT + (size_t)(r1 + c0) * FEAT_CH + nb4);
        v4f B1 = *(const v4f*)(fT + (size_t)(r1 + c1) * FEAT_CH + nb4);
        v4f B2 = *(const v4f*)(fT + (size_t)(r1 + c2) * FEAT_CH + nb4);
        v4f B3 = *(const v4f*)(fT + (size_t)(r1 + c3) * FEAT_CH + nb4);

        float nr[8], dt[8];
        v8s Bfrag[4];

        if (col != 0 && col != 14) {
            // interior: (L,tx) per j is compile-time; one M v4f live at a time
#define PXJ(J, TX, TL, TR, BL, BR) { \
            const v4f Mj = *(const v4f*)(mn + (size_t)segj[J] * FEAT_CH + nb4); \
            float nrj = 0.0f, dtj = 0.0f; \
            _Pragma("unroll") \
            for (int t = 0; t < 4; ++t) { \
                float tp = fmaf(TX, TR[t] - TL[t], TL[t]); \
                float bt = fmaf(TX, BR[t] - BL[t], BL[t]); \
                float v  = fmaf(ty, bt - tp, tp); \
                nrj = fmaf(v, v, nrj); \
                dtj = fmaf(v, Mj[t], dtj); \
                Bfrag[t][J] = f2bf(v); } \
            nr[J] = nrj; dt[J] = dtj; }
            PXJ(0, 0.625f, T0, T1, B0, B1)
            PXJ(1, 0.875f, T0, T1, B0, B1)
            PXJ(2, 0.125f, T1, T2, B1, B2)
            PXJ(3, 0.375f, T1, T2, B1, B2)
            PXJ(4, 0.625f, T1, T2, B1, B2)
            PXJ(5, 0.875f, T1, T2, B1, B2)
            PXJ(6, 0.125f, T2, T3, B2, B3)
            PXJ(7, 0.375f, T2, T3, B2, B3)
#undef PXJ
        } else {
#pragma unroll
            for (int j = 0; j < 8; ++j) {
                float fx = fminf(fmaxf((float)(px0 + j) * 0.25f - 0.375f, 0.0f), 119.0f);
                const int x0 = (int)fx;
                const float tx = fx - (float)x0;
                const int L = x0 - base + 1;  // 0..2
                const v4f Mj = *(const v4f*)(mn + (size_t)segj[j] * FEAT_CH + nb4);
                float nrj = 0.0f, dtj = 0.0f;
#pragma unroll
                for (int t = 0; t < 4; ++t) {
                    float tl = (L==0)?T0[t]:((L==1)?T1[t]:T2[t]);
                    float tr = (L==0)?T1[t]:((L==1)?T2[t]:T3[t]);
                    float bl = (L==0)?B0[t]:((L==1)?B1[t]:B2[t]);
                    float br = (L==0)?B1[t]:((L==1)?B2[t]:B3[t]);
                    float tp = fmaf(tx, tr - tl, tl);
                    float bt = fmaf(tx, br - bl, bl);
                    float v  = fmaf(ty, bt - tp, tp);
                    nrj = fmaf(v, v, nrj);
                    dtj = fmaf(v, Mj[t], dtj);
                    Bfrag[t][j] = f2bf(v);
                }
                nr[j] = nrj; dt[j] = dtj;
            }
        }

        // per-pixel reduce over 16 ch-lanes (within the kg row of 16)
#pragma unroll
        for (int j = 0; j < 8; ++j) reduce16_pair(nr[j], dt[j]);

        float wj[8]; short wb[8];
#pragma unroll
        for (int j = 0; j < 8; ++j) {
            wj[j] = 1.0f - dt[j] / fmaxf(sqrtf(nr[j]), EPSV);  // mn==0 rows -> w==1
            wb[j] = f2bf(wj[j]);
        }
        // one-hot A per class band, 4 MFMAs each
#pragma unroll
        for (int b = 0; b < 8; ++b) {
            v8s A;
#pragma unroll
            for (int j = 0; j < 8; ++j)
                A[j] = (segj[j] == b * 16 + n) ? wb[j] : (short)0;
#pragma unroll
            for (int t = 0; t < 4; ++t)
                C[b][t] = __builtin_amdgcn_mfma_f32_16x16x32_bf16(A, Bfrag[t], C[b][t], 0, 0, 0);
        }
        // wsum / count (LDS atomics, lanes n==0 only)
        if (n == 0) {
#pragma unroll
            for (int j = 0; j < 8; ++j) {
                atomicAdd(&accL[segj[j] * STRIDE_ACC + FEAT_CH], wj[j]);
                atomicAdd(&cntL[segj[j]], 1.0f);
            }
        }
    }

    // concurrent merge: all waves ds_add_f32 into accL in parallel (no barrier
    // needed vs main-loop stragglers: every accL access is atomic; merge cols
    // 0..63 are disjoint from the wsum col 64). Banks are 2-way = free.
#pragma unroll
    for (int b = 0; b < 8; ++b)
#pragma unroll
        for (int t = 0; t < 4; ++t)
#pragma unroll
            for (int r = 0; r < 4; ++r)
                atomicAdd(&accL[(b * 16 + kg * 4 + r) * STRIDE_ACC + t * 16 + n],
                          C[b][t][r]);
    __syncthreads();

    // writeout: plain coalesced dwordx4 stores of the block partial (no atomics)
    float* __restrict__ dst = part + (size_t)blockIdx.x * ACC_TOTAL;
    v4f* __restrict__ d4 = (v4f*)dst;
    const v4f* __restrict__ s4 = (const v4f*)accL;
    for (int i = tid; i < ACC_FLOATS / 4; i += 512) d4[i] = s4[i];
    if (tid < NCLS_PAD) dst[ACC_FLOATS + tid] = cntL[tid];
}

// ---- phase 1b: tree-reduce partials into red[NRED][ACC_TOTAL] (no atomics) ---
__global__ __launch_bounds__(256) void k_reduce(
        const float* __restrict__ part, float* __restrict__ red, int nb) {
    const int i = blockIdx.x * 256 + threadIdx.x;    // slot
    if (i >= ACC_TOTAL) return;
    const int chunk = (nb + NRED - 1) / NRED;
    const int b0 = blockIdx.y * chunk;
    const int b1 = min(nb, b0 + chunk);
    float s = 0.0f;
    for (int b = b0; b < b1; ++b) s += part[(size_t)b * ACC_TOTAL + i];
    red[(size_t)blockIdx.y * ACC_TOTAL + i] = s;
}

// ---- phase 2: sum group partials + momentum / is_zero / present selects ------
__global__ void k_final(const float* __restrict__ red, const float* __restrict__ mem,
                        float* __restrict__ out) {
    const int c = blockIdx.x, k = threadIdx.x;   // 124 blocks x 64 threads (1 wave)
    float a = 0.0f, wsum = 0.0f, cnt = 0.0f;
#pragma unroll
    for (int g = 0; g < NRED; ++g) {
        const float* r = red + (size_t)g * ACC_TOTAL;
        a    += r[c * STRIDE_ACC + k];
        wsum += r[c * STRIDE_ACC + FEAT_CH];
        cnt  += r[ACC_FLOATS + c];
    }
    const float m = mem[c * FEAT_CH + k];
    const int is_zero = __all(m == 0.0f);
    const float divisor = (wsum > 0.0f) ? wsum : 1.0f;
    const float val = a / divisor;
    const float nw = is_zero ? val : fmaf(0.1f, val, 0.9f * m);
    out[c * FEAT_CH + k] = (cnt > 0.0f) ? nw : m;
}

extern "C" void kernel_launch(void* const* d_in, const int* in_sizes, int n_in,
                              void* d_out, int out_size, void* d_ws, size_t ws_size,
                              hipStream_t stream) {
    const float* feats  = (const float*)d_in[0];   // (1,64,120,120) f32
    const float* memory = (const float*)d_in[1];   // (124,1,64) f32
    const int*   seg    = (const int*)d_in[2];     // (1,480,480) i32
    float* out = (float*)d_out;                    // (124,1,64) f32
    float* ws  = (float*)d_ws;

    float* mn   = ws + WS_MN;
    float* red  = ws + WS_RED;
    float* fT   = ws + WS_FT;
    float* part = ws + WS_PART;

    long long avail = (long long)(ws_size / 4) - WS_PART;
    const int nb = (avail >= (long long)256 * ACC_TOTAL) ? 256 : 128;

    k_prep<<<NUM_CLASSES + NTILE, 256, 0, stream>>>(memory, feats, mn, fT);
    k_accum<<<nb, 512, 0, stream>>>(fT, seg, mn, part);
    dim3 rg((ACC_TOTAL + 255) / 256, NRED);
    k_reduce<<<rg, 256, 0, stream>>>(part, red, nb);
    k_final<<<NUM_CLASSES, FEAT_CH, 0, stream>>>(red, memory, out);
}